// Round 1
// baseline (3609.298 us; speedup 1.0000x reference)
//
#include <hip/hip_runtime.h>
#include <math.h>

#define NB   16
#define NPT  2048
#define NF   512
#define BI   128
#define BJ   128
#define KF   32
#define NTHR 256
#define NJT  (NPT / BJ)   // 16
#define NIT  (NPT / BI)   // 16
#define NKC  (NF / KF)    // 16

// ---------------------------------------------------------------------------
// Kernel A: fused logits-GEMM + online column-softmax + PV + per-block
// partial sums for means / 3x3 cross-covariance.
//   logits[i,j] = sum_f ftarget[b,f,i] * fsource[b,f,j]
//   weight      = softmax over i (per column j)
//   pred[c,j]   = sum_i target[b,i,c] * weight[i,j]
// Each block: one batch b, one 128-wide j-tile. Streams 16 i-tiles of 128.
// ---------------------------------------------------------------------------
__global__ __launch_bounds__(NTHR)
void attn_partials_kernel(const float* __restrict__ source,
                          const float* __restrict__ target,
                          const float* __restrict__ fsource,
                          const float* __restrict__ ftarget,
                          float* __restrict__ partials)
{
    const int b   = blockIdx.x;   // batch on grid-x so linear id % 8 groups same batch per XCD
    const int jt  = blockIdx.y;
    const int j0  = jt * BJ;
    const int tid = threadIdx.x;
    const int tx  = tid & 15;
    const int ty  = tid >> 4;

    __shared__ float  As[KF * BI];       // ftarget chunk [k][i]
    __shared__ float  Bs[KF * BJ];       // fsource chunk [k][j]
    __shared__ float  red[16 * BJ];      // per-ty-group column max partials
    __shared__ float4 red4[16 * BJ];     // per-ty-group (z, y0, y1, y2) partials
    __shared__ float  tgts[3][BI];       // target coords of current i-tile
    __shared__ float  stM[BJ];           // running max per column
    __shared__ float  stZ[BJ];           // running denom
    __shared__ float  stY[3][BJ];        // running weighted target sums
    __shared__ float  colm[BJ];          // broadcast of new max
    __shared__ float  fin[4][15];        // cross-wave final reduce

    if (tid < BJ) {
        stM[tid] = -3.0e38f;
        stZ[tid] = 0.0f;
        stY[0][tid] = 0.0f; stY[1][tid] = 0.0f; stY[2][tid] = 0.0f;
    }

    const size_t fbase = (size_t)b * NF * NPT;

    float4 sA[4], sB[4];

    for (int it = 0; it < NIT; ++it) {
        const int i0 = it * BI;

        float acc[8][8];
        #pragma unroll
        for (int ii = 0; ii < 8; ++ii)
            #pragma unroll
            for (int jj = 0; jj < 8; ++jj)
                acc[ii][jj] = 0.0f;

        // ---- prologue: stage F-chunk 0 (regs -> LDS), load target coords ----
        #pragma unroll
        for (int p = 0; p < 4; ++p) {
            const int q  = tid + p * NTHR;
            const int k  = q >> 5;
            const int c4 = (q & 31) << 2;
            sA[p] = *(const float4*)(ftarget + fbase + (size_t)k * NPT + i0 + c4);
            sB[p] = *(const float4*)(fsource + fbase + (size_t)k * NPT + j0 + c4);
        }
        if (tid < BI) {
            const float* tp = target + ((size_t)b * NPT + i0 + tid) * 3;
            tgts[0][tid] = tp[0];
            tgts[1][tid] = tp[1];
            tgts[2][tid] = tp[2];
        }
        #pragma unroll
        for (int p = 0; p < 4; ++p) {
            const int q  = tid + p * NTHR;
            const int k  = q >> 5;
            const int c4 = (q & 31) << 2;
            *(float4*)&As[k * BI + c4] = sA[p];
            *(float4*)&Bs[k * BJ + c4] = sB[p];
        }
        __syncthreads();

        // ---- main F-chunk loop: prefetch next chunk, compute current ----
        for (int kc = 0; kc < NKC; ++kc) {
            if (kc + 1 < NKC) {
                #pragma unroll
                for (int p = 0; p < 4; ++p) {
                    const int q  = tid + p * NTHR;
                    const int k  = q >> 5;
                    const int c4 = (q & 31) << 2;
                    const size_t row = (size_t)((kc + 1) * KF + k) * NPT;
                    sA[p] = *(const float4*)(ftarget + fbase + row + i0 + c4);
                    sB[p] = *(const float4*)(fsource + fbase + row + j0 + c4);
                }
            }
            #pragma unroll
            for (int k = 0; k < KF; ++k) {
                const float4 a0 = *(const float4*)&As[k * BI + (ty << 2)];
                const float4 a1 = *(const float4*)&As[k * BI + 64 + (ty << 2)];
                const float4 b0 = *(const float4*)&Bs[k * BJ + (tx << 2)];
                const float4 b1 = *(const float4*)&Bs[k * BJ + 64 + (tx << 2)];
                const float av[8] = {a0.x, a0.y, a0.z, a0.w, a1.x, a1.y, a1.z, a1.w};
                const float bv[8] = {b0.x, b0.y, b0.z, b0.w, b1.x, b1.y, b1.z, b1.w};
                #pragma unroll
                for (int ii = 0; ii < 8; ++ii)
                    #pragma unroll
                    for (int jj = 0; jj < 8; ++jj)
                        acc[ii][jj] = fmaf(av[ii], bv[jj], acc[ii][jj]);
            }
            __syncthreads();
            if (kc + 1 < NKC) {
                #pragma unroll
                for (int p = 0; p < 4; ++p) {
                    const int q  = tid + p * NTHR;
                    const int k  = q >> 5;
                    const int c4 = (q & 31) << 2;
                    *(float4*)&As[k * BI + c4] = sA[p];
                    *(float4*)&Bs[k * BJ + c4] = sB[p];
                }
                __syncthreads();
            }
        }

        // ---- phase 3: per-column tile max ----
        #pragma unroll
        for (int jj = 0; jj < 8; ++jj) {
            float m = acc[0][jj];
            #pragma unroll
            for (int ii = 1; ii < 8; ++ii) m = fmaxf(m, acc[ii][jj]);
            const int jL = (jj < 4) ? ((tx << 2) + jj) : (64 + (tx << 2) + (jj - 4));
            red[ty * BJ + jL] = m;
        }
        __syncthreads();

        float m_old = 0.0f, m_new = 0.0f;
        if (tid < BJ) {
            float m = red[tid];
            #pragma unroll
            for (int g = 1; g < 16; ++g) m = fmaxf(m, red[g * BJ + tid]);
            m_old = stM[tid];
            m_new = fmaxf(m_old, m);
            colm[tid] = m_new;
        }
        __syncthreads();

        // ---- phase 4: exp + partial (Z, y) sums ----
        #pragma unroll
        for (int jj = 0; jj < 8; ++jj) {
            const int jL = (jj < 4) ? ((tx << 2) + jj) : (64 + (tx << 2) + (jj - 4));
            const float m = colm[jL];
            float z = 0.0f, y0 = 0.0f, y1 = 0.0f, y2 = 0.0f;
            #pragma unroll
            for (int ii = 0; ii < 8; ++ii) {
                const int iL = (ii < 4) ? ((ty << 2) + ii) : (64 + (ty << 2) + (ii - 4));
                const float e = __expf(acc[ii][jj] - m);
                z += e;
                y0 = fmaf(e, tgts[0][iL], y0);
                y1 = fmaf(e, tgts[1][iL], y1);
                y2 = fmaf(e, tgts[2][iL], y2);
            }
            red4[ty * BJ + jL] = make_float4(z, y0, y1, y2);
        }
        __syncthreads();

        // ---- phase 5: fold into running state ----
        if (tid < BJ) {
            float z = 0.0f, y0 = 0.0f, y1 = 0.0f, y2 = 0.0f;
            #pragma unroll
            for (int g = 0; g < 16; ++g) {
                const float4 v = red4[g * BJ + tid];
                z += v.x; y0 += v.y; y1 += v.z; y2 += v.w;
            }
            const float r = __expf(m_old - m_new);
            stZ[tid]    = stZ[tid]    * r + z;
            stY[0][tid] = stY[0][tid] * r + y0;
            stY[1][tid] = stY[1][tid] * r + y1;
            stY[2][tid] = stY[2][tid] * r + y2;
            stM[tid] = m_new;
        }
        __syncthreads();
    }

    // ---- finalize: per-block sums of src, pred, src⊗pred ----
    float v[15];
    #pragma unroll
    for (int q = 0; q < 15; ++q) v[q] = 0.0f;
    if (tid < BJ) {
        const float iz = 1.0f / stZ[tid];
        const float p0 = stY[0][tid] * iz;
        const float p1 = stY[1][tid] * iz;
        const float p2 = stY[2][tid] * iz;
        const float* sp = source + ((size_t)b * NPT + j0 + tid) * 3;
        const float s0 = sp[0], s1 = sp[1], s2 = sp[2];
        v[0] = s0; v[1] = s1; v[2] = s2;
        v[3] = p0; v[4] = p1; v[5] = p2;
        v[6]  = s0 * p0; v[7]  = s0 * p1; v[8]  = s0 * p2;
        v[9]  = s1 * p0; v[10] = s1 * p1; v[11] = s1 * p2;
        v[12] = s2 * p0; v[13] = s2 * p1; v[14] = s2 * p2;
    }
    #pragma unroll
    for (int q = 0; q < 15; ++q)
        #pragma unroll
        for (int off = 32; off > 0; off >>= 1)
            v[q] += __shfl_down(v[q], off);
    const int wv = tid >> 6, ln = tid & 63;
    if (ln == 0) {
        #pragma unroll
        for (int q = 0; q < 15; ++q) fin[wv][q] = v[q];
    }
    __syncthreads();
    if (tid == 0) {
        float* o = partials + (((size_t)b << 4) + jt) * 16;
        #pragma unroll
        for (int q = 0; q < 15; ++q)
            o[q] = fin[0][q] + fin[1][q] + fin[2][q] + fin[3][q];
    }
}

// ---------------------------------------------------------------------------
// Kernel B: per-batch 3x3 covariance -> SVD (Jacobi on S^T S) -> R, t
// ---------------------------------------------------------------------------
__device__ inline void jrot(float A[3][3], float V[3][3], int p, int q)
{
    const float apq = A[p][q];
    if (fabsf(apq) < 1e-28f) return;
    const float tau = (A[q][q] - A[p][p]) / (2.0f * apq);
    const float t   = (tau >= 0.0f ? 1.0f : -1.0f) / (fabsf(tau) + sqrtf(1.0f + tau * tau));
    const float c   = rsqrtf(1.0f + t * t);
    const float s   = t * c;
    const float app = A[p][p], aqq = A[q][q];
    A[p][p] = app - t * apq;
    A[q][q] = aqq + t * apq;
    A[p][q] = 0.0f; A[q][p] = 0.0f;
    const int r = 3 - p - q;
    const float arp = A[r][p], arq = A[r][q];
    A[r][p] = c * arp - s * arq; A[p][r] = A[r][p];
    A[r][q] = s * arp + c * arq; A[q][r] = A[r][q];
    #pragma unroll
    for (int rr = 0; rr < 3; ++rr) {
        const float vrp = V[rr][p], vrq = V[rr][q];
        V[rr][p] = c * vrp - s * vrq;
        V[rr][q] = s * vrp + c * vrq;
    }
}

__global__ void svd_finalize_kernel(const float* __restrict__ partials,
                                    float* __restrict__ out)
{
    const int b = threadIdx.x;
    if (b >= NB) return;

    float srcS[3] = {0, 0, 0}, predS[3] = {0, 0, 0}, SP[9] = {0, 0, 0, 0, 0, 0, 0, 0, 0};
    for (int p = 0; p < NJT; ++p) {
        const float* vv = partials + (((size_t)b << 4) + p) * 16;
        srcS[0] += vv[0]; srcS[1] += vv[1]; srcS[2] += vv[2];
        predS[0] += vv[3]; predS[1] += vv[4]; predS[2] += vv[5];
        #pragma unroll
        for (int q = 0; q < 9; ++q) SP[q] += vv[6 + q];
    }

    const float invN = 1.0f / (float)NPT;
    float ms[3], mt[3];
    #pragma unroll
    for (int c = 0; c < 3; ++c) { ms[c] = srcS[c] * invN; mt[c] = predS[c] * invN; }

    float S[3][3];
    #pragma unroll
    for (int c = 0; c < 3; ++c)
        #pragma unroll
        for (int d = 0; d < 3; ++d)
            S[c][d] = SP[c * 3 + d] - srcS[c] * predS[d] * invN;

    // A = S^T S (symmetric PSD)
    float A[3][3];
    #pragma unroll
    for (int i = 0; i < 3; ++i)
        #pragma unroll
        for (int j = 0; j < 3; ++j)
            A[i][j] = S[0][i] * S[0][j] + S[1][i] * S[1][j] + S[2][i] * S[2][j];

    float V[3][3] = {{1, 0, 0}, {0, 1, 0}, {0, 0, 1}};
    for (int sweep = 0; sweep < 12; ++sweep) {
        jrot(A, V, 0, 1);
        jrot(A, V, 0, 2);
        jrot(A, V, 1, 2);
    }

    // sort eigenvalues descending, permute V columns
    float lam[3] = {A[0][0], A[1][1], A[2][2]};
    for (int i = 0; i < 2; ++i) {
        int mx = i;
        for (int j = i + 1; j < 3; ++j) if (lam[j] > lam[mx]) mx = j;
        if (mx != i) {
            const float tl = lam[i]; lam[i] = lam[mx]; lam[mx] = tl;
            #pragma unroll
            for (int r = 0; r < 3; ++r) {
                const float tv = V[r][i]; V[r][i] = V[r][mx]; V[r][mx] = tv;
            }
        }
    }

    // U columns: u1 = S v1 / |S v1|, u2 = GS(S v2), u3 = u1 x u2  (det(U)=+1)
    float w0[3], w1[3], u1[3], u2[3], u3[3];
    #pragma unroll
    for (int r = 0; r < 3; ++r) {
        w0[r] = S[r][0] * V[0][0] + S[r][1] * V[1][0] + S[r][2] * V[2][0];
        w1[r] = S[r][0] * V[0][1] + S[r][1] * V[1][1] + S[r][2] * V[2][1];
    }
    const float n1 = sqrtf(w0[0] * w0[0] + w0[1] * w0[1] + w0[2] * w0[2]) + 1e-30f;
    #pragma unroll
    for (int r = 0; r < 3; ++r) u1[r] = w0[r] / n1;
    const float d01 = u1[0] * w1[0] + u1[1] * w1[1] + u1[2] * w1[2];
    #pragma unroll
    for (int r = 0; r < 3; ++r) u2[r] = w1[r] - d01 * u1[r];
    const float n2 = sqrtf(u2[0] * u2[0] + u2[1] * u2[1] + u2[2] * u2[2]) + 1e-30f;
    #pragma unroll
    for (int r = 0; r < 3; ++r) u2[r] /= n2;
    u3[0] = u1[1] * u2[2] - u1[2] * u2[1];
    u3[1] = u1[2] * u2[0] - u1[0] * u2[2];
    u3[2] = u1[0] * u2[1] - u1[1] * u2[0];

    // d = det(V) (det(U) = +1 by construction); R = V diag(1,1,d) U^T
    const float detV =
        V[0][0] * (V[1][1] * V[2][2] - V[1][2] * V[2][1]) -
        V[0][1] * (V[1][0] * V[2][2] - V[1][2] * V[2][0]) +
        V[0][2] * (V[1][0] * V[2][1] - V[1][1] * V[2][0]);

    float R[3][3];
    #pragma unroll
    for (int r = 0; r < 3; ++r)
        #pragma unroll
        for (int c = 0; c < 3; ++c)
            R[r][c] = V[r][0] * u1[c] + V[r][1] * u2[c] + detV * V[r][2] * u3[c];

    #pragma unroll
    for (int r = 0; r < 3; ++r)
        #pragma unroll
        for (int c = 0; c < 3; ++c)
            out[b * 9 + r * 3 + c] = R[r][c];

    #pragma unroll
    for (int r = 0; r < 3; ++r) {
        const float tr = mt[r] - (R[r][0] * ms[0] + R[r][1] * ms[1] + R[r][2] * ms[2]);
        out[NB * 9 + b * 3 + r] = tr;
    }
}

extern "C" void kernel_launch(void* const* d_in, const int* in_sizes, int n_in,
                              void* d_out, int out_size, void* d_ws, size_t ws_size,
                              hipStream_t stream)
{
    const float* source  = (const float*)d_in[0];
    const float* target  = (const float*)d_in[1];
    const float* fsource = (const float*)d_in[2];
    const float* ftarget = (const float*)d_in[3];
    float* partials = (float*)d_ws;   // 256 blocks x 16 floats
    float* out = (float*)d_out;

    dim3 grid(NB, NJT);
    attn_partials_kernel<<<grid, NTHR, 0, stream>>>(source, target, fsource, ftarget, partials);
    svd_finalize_kernel<<<1, 64, 0, stream>>>(partials, out);
}

// Round 3
// 315.401 us; speedup vs baseline: 11.4435x; 11.4435x over previous
//
#include <hip/hip_runtime.h>
#include <math.h>
#include <stdint.h>

#define NB   16
#define NPT  2048
#define NF   512
#define BI   128
#define BJ   128
#define KB   32
#define NTHR 512
#define NJT  (NPT / BJ)   // 16
#define NIT  (NPT / BI)   // 16
#define NKC  (NF / KB)    // 16

// LDS tile geometry (bytes). Per plane: 8 col-groups of 16 cols.
// Col-group: [k-half h][k-group g][4 rows][16 cols] fp16, h-stride 512B,
// g-stride 128B. Col-group stride padded 1024->1056B (=32B mod 128) so the
// staging ds_write_b64s spread across bank pairs (2-way = free) instead of
// 8-way aliasing banks 0-7.
#define CGS   1056
#define PLANE 8448            // 8 * CGS
#define PLANE_H 4224          // halves
#define BUFB  33792           // 4 planes (Ahi, Alo, Bhi, Blo)

typedef _Float16 h4 __attribute__((ext_vector_type(4)));
typedef _Float16 h8 __attribute__((ext_vector_type(8)));
typedef float    f32x4 __attribute__((ext_vector_type(4)));

// ds_read_b64_tr_b16 with NATURAL per-lane addressing (base + lane*8): the
// 64 lanes cover a 512B region = [16k][16col] fp16 subtile; HW transposes so
// lane l receives col (l&15), k = 4*(l>>4) + j  (j = elem 0..3). [m156/m162]
#define TRR(dst, a) asm volatile("ds_read_b64_tr_b16 %0, %1" : "=v"(dst) : "v"(a))

__device__ __forceinline__ h8 cat(h4 a, h4 b) {
    return __builtin_shufflevector(a, b, 0, 1, 2, 3, 4, 5, 6, 7);
}

// fp32 -> fp16 hi/lo split: x = hi + lo + O(2^-24 |x|)
__device__ __forceinline__ void cvt4(const float4 v, h4& hi, h4& lo) {
    hi[0] = (_Float16)v.x; hi[1] = (_Float16)v.y;
    hi[2] = (_Float16)v.z; hi[3] = (_Float16)v.w;
    lo[0] = (_Float16)(v.x - (float)hi[0]);
    lo[1] = (_Float16)(v.y - (float)hi[1]);
    lo[2] = (_Float16)(v.z - (float)hi[2]);
    lo[3] = (_Float16)(v.w - (float)hi[3]);
}

// ---------------------------------------------------------------------------
// Kernel A: fused logits MFMA-GEMM (fp16 hi/lo split = fp32-accurate) +
// online column-softmax + PV + per-block partials for means / 3x3 covariance.
// Block = (batch b, 128-wide j-tile). 8 waves: wi (i-half) x wj (j-quarter).
// ---------------------------------------------------------------------------
__global__ __launch_bounds__(NTHR, 2)
void attn_partials_kernel(const float* __restrict__ source,
                          const float* __restrict__ target,
                          const float* __restrict__ fsource,
                          const float* __restrict__ ftarget,
                          float* __restrict__ partials)
{
    const int b    = blockIdx.x;   // batch fast -> same-batch blocks share XCD L2
    const int jt   = blockIdx.y;
    const int j0   = jt * BJ;
    const int tid  = threadIdx.x;
    const int lane = tid & 63;
    const int wave = tid >> 6;     // 0..7
    const int wi   = wave >> 2;    // i-half: rows [wi*64, wi*64+64)
    const int wj   = wave & 3;     // j-quarter: cols [wj*32, wj*32+32)
    const int lg   = lane >> 4;    // 0..3
    const int lr   = lane & 15;

    __shared__ __align__(16) _Float16 TILES[2][4][PLANE_H]; // [buf][Ahi,Alo,Bhi,Blo]
    __shared__ float  tgts[3][BI];
    __shared__ float  redM[2][BJ];     // per-wi-half column max
    __shared__ float4 redS[2][BJ];     // per-wi-half (z,y0,y1,y2)
    __shared__ float  predL[3][BJ];
    __shared__ float  fin[8][15];

    const uint32_t tilesBase = (uint32_t)(uintptr_t)&TILES[0][0][0];
    const uint32_t trLane    = (uint32_t)(lane * 8);

    const size_t fbase = (size_t)b * NF * NPT;

    float Mrun[2], Zrun[2], Yrun[2][3];
    #pragma unroll
    for (int n = 0; n < 2; ++n) {
        Mrun[n] = -3.0e38f; Zrun[n] = 0.0f;
        Yrun[n][0] = 0.0f; Yrun[n][1] = 0.0f; Yrun[n][2] = 0.0f;
    }

    float4 gA[2], gB[2];

    for (int it = 0; it < NIT; ++it) {
        const int i0 = it * BI;

        // ---- prologue: stage chunk 0 into buf0 + target coords ----
        #pragma unroll
        for (int p = 0; p < 2; ++p) {
            const int q = tid + p * NTHR;
            const int f = q >> 5, i4 = q & 31;
            gA[p] = *(const float4*)(ftarget + fbase + (size_t)f * NPT + i0 + i4 * 4);
            gB[p] = *(const float4*)(fsource + fbase + (size_t)f * NPT + j0 + i4 * 4);
        }
        if (tid < BI) {
            const float* tp = target + ((size_t)b * NPT + i0 + tid) * 3;
            tgts[0][tid] = tp[0]; tgts[1][tid] = tp[1]; tgts[2][tid] = tp[2];
        }
        #pragma unroll
        for (int p = 0; p < 2; ++p) {
            const int q = tid + p * NTHR;
            const int f = q >> 5, i4 = q & 31;
            // halves offset within a plane
            const int hoff = (i4 >> 2) * 528 + (f >> 4) * 256 + ((f >> 2) & 3) * 64
                           + (f & 3) * 16 + (i4 & 3) * 4;
            _Float16* bp = &TILES[0][0][0];
            h4 hi, lo;
            cvt4(gA[p], hi, lo);
            *(h4*)(bp + hoff)               = hi;   // A hi
            *(h4*)(bp + PLANE_H + hoff)     = lo;   // A lo
            cvt4(gB[p], hi, lo);
            *(h4*)(bp + 2 * PLANE_H + hoff) = hi;   // B hi
            *(h4*)(bp + 3 * PLANE_H + hoff) = lo;   // B lo
        }
        __syncthreads();

        f32x4 acc[4][2];
        #pragma unroll
        for (int m = 0; m < 4; ++m)
            #pragma unroll
            for (int n = 0; n < 2; ++n)
                acc[m][n] = (f32x4){0.0f, 0.0f, 0.0f, 0.0f};

        for (int kc = 0; kc < NKC; ++kc) {
            const int buf = kc & 1;
            // prefetch next chunk's globals (latency hides under MFMA)
            if (kc + 1 < NKC) {
                #pragma unroll
                for (int p = 0; p < 2; ++p) {
                    const int q = tid + p * NTHR;
                    const int f = q >> 5, i4 = q & 31;
                    const size_t row = (size_t)((kc + 1) * KB + f) * NPT;
                    gA[p] = *(const float4*)(ftarget + fbase + row + i0 + i4 * 4);
                    gB[p] = *(const float4*)(fsource + fbase + row + j0 + i4 * 4);
                }
            }
            // fragment tr-reads: col-group C at C*CGS, k-half at +512
            const uint32_t bufB = tilesBase + (uint32_t)buf * BUFB;
            const uint32_t aHi  = bufB + (uint32_t)(wi * 4) * CGS + trLane;
            const uint32_t bHi  = bufB + 2u * PLANE + (uint32_t)(wj * 2) * CGS + trLane;
            h4 ta[4][2][2], tb[2][2][2];   // [frag][hi/lo][k-half]
            #pragma unroll
            for (int n = 0; n < 2; ++n) {
                TRR(tb[n][0][0], bHi + n * CGS);
                TRR(tb[n][0][1], bHi + n * CGS + 512);
                TRR(tb[n][1][0], bHi + n * CGS + PLANE);
                TRR(tb[n][1][1], bHi + n * CGS + PLANE + 512);
            }
            #pragma unroll
            for (int m = 0; m < 4; ++m) {
                TRR(ta[m][0][0], aHi + m * CGS);
                TRR(ta[m][0][1], aHi + m * CGS + 512);
                TRR(ta[m][1][0], aHi + m * CGS + PLANE);
                TRR(ta[m][1][1], aHi + m * CGS + PLANE + 512);
            }
            asm volatile("s_waitcnt lgkmcnt(0)" ::: "memory");
            __builtin_amdgcn_sched_barrier(0);   // rule #18: fence MFMA below the wait

            h8 Bh[2], Bl[2];
            #pragma unroll
            for (int n = 0; n < 2; ++n) {
                Bh[n] = cat(tb[n][0][0], tb[n][0][1]);
                Bl[n] = cat(tb[n][1][0], tb[n][1][1]);
            }
            #pragma unroll
            for (int m = 0; m < 4; ++m) {
                const h8 Ah = cat(ta[m][0][0], ta[m][0][1]);
                const h8 Al = cat(ta[m][1][0], ta[m][1][1]);
                #pragma unroll
                for (int n = 0; n < 2; ++n) {
                    acc[m][n] = __builtin_amdgcn_mfma_f32_16x16x32_f16(Ah, Bh[n], acc[m][n], 0, 0, 0);
                    acc[m][n] = __builtin_amdgcn_mfma_f32_16x16x32_f16(Ah, Bl[n], acc[m][n], 0, 0, 0);
                    acc[m][n] = __builtin_amdgcn_mfma_f32_16x16x32_f16(Al, Bh[n], acc[m][n], 0, 0, 0);
                }
            }
            // write next chunk into the other buffer; one barrier per K-step
            if (kc + 1 < NKC) {
                #pragma unroll
                for (int p = 0; p < 2; ++p) {
                    const int q = tid + p * NTHR;
                    const int f = q >> 5, i4 = q & 31;
                    const int hoff = (i4 >> 2) * 528 + (f >> 4) * 256 + ((f >> 2) & 3) * 64
                                   + (f & 3) * 16 + (i4 & 3) * 4;
                    _Float16* bp = &TILES[buf ^ 1][0][0];
                    h4 hi, lo;
                    cvt4(gA[p], hi, lo);
                    *(h4*)(bp + hoff)               = hi;
                    *(h4*)(bp + PLANE_H + hoff)     = lo;
                    cvt4(gB[p], hi, lo);
                    *(h4*)(bp + 2 * PLANE_H + hoff) = hi;
                    *(h4*)(bp + 3 * PLANE_H + hoff) = lo;
                }
                __syncthreads();
            }
        }

        // ---- online softmax update for this i-tile ----
        // D layout (m89): col j = wj*32+n*16+lr, row i = wi*64+m*16+lg*4+r
        float mnew[2];
        #pragma unroll
        for (int n = 0; n < 2; ++n) {
            float m = acc[0][n][0];
            #pragma unroll
            for (int mm = 0; mm < 4; ++mm)
                #pragma unroll
                for (int r = 0; r < 4; ++r)
                    m = fmaxf(m, acc[mm][n][r]);
            m = fmaxf(m, __shfl_xor(m, 16));
            m = fmaxf(m, __shfl_xor(m, 32));
            if (lane < 16) redM[wi][wj * 32 + n * 16 + lr] = m;
        }
        __syncthreads();
        #pragma unroll
        for (int n = 0; n < 2; ++n) {
            const int col = wj * 32 + n * 16 + lr;
            mnew[n] = fmaxf(Mrun[n], fmaxf(redM[0][col], redM[1][col]));
        }

        float z[2] = {0.0f, 0.0f}, y[2][3] = {{0, 0, 0}, {0, 0, 0}};
        #pragma unroll
        for (int mm = 0; mm < 4; ++mm)
            #pragma unroll
            for (int r = 0; r < 4; ++r) {
                const int iL = wi * 64 + mm * 16 + lg * 4 + r;
                const float t0 = tgts[0][iL], t1 = tgts[1][iL], t2 = tgts[2][iL];
                #pragma unroll
                for (int n = 0; n < 2; ++n) {
                    const float e = __expf(acc[mm][n][r] - mnew[n]);
                    z[n] += e;
                    y[n][0] = fmaf(e, t0, y[n][0]);
                    y[n][1] = fmaf(e, t1, y[n][1]);
                    y[n][2] = fmaf(e, t2, y[n][2]);
                }
            }
        #pragma unroll
        for (int n = 0; n < 2; ++n) {
            #pragma unroll
            for (int off = 16; off <= 32; off <<= 1) {
                z[n]    += __shfl_xor(z[n], off);
                y[n][0] += __shfl_xor(y[n][0], off);
                y[n][1] += __shfl_xor(y[n][1], off);
                y[n][2] += __shfl_xor(y[n][2], off);
            }
            if (lane < 16)
                redS[wi][wj * 32 + n * 16 + lr] = make_float4(z[n], y[n][0], y[n][1], y[n][2]);
        }
        __syncthreads();
        #pragma unroll
        for (int n = 0; n < 2; ++n) {
            const int col = wj * 32 + n * 16 + lr;
            const float4 s0 = redS[0][col], s1 = redS[1][col];
            const float sc = __expf(Mrun[n] - mnew[n]);
            Zrun[n]    = Zrun[n]    * sc + s0.x + s1.x;
            Yrun[n][0] = Yrun[n][0] * sc + s0.y + s1.y;
            Yrun[n][1] = Yrun[n][1] * sc + s0.z + s1.z;
            Yrun[n][2] = Yrun[n][2] * sc + s0.w + s1.w;
            Mrun[n] = mnew[n];
        }
    }

    // ---- epilogue: pred = Y/Z, then 15 partial sums for this block ----
    if (lane < 16) {
        #pragma unroll
        for (int n = 0; n < 2; ++n) {
            const int col = wj * 32 + n * 16 + lr;
            const float iz = 1.0f / Zrun[n];
            predL[0][col] = Yrun[n][0] * iz;
            predL[1][col] = Yrun[n][1] * iz;
            predL[2][col] = Yrun[n][2] * iz;
        }
    }
    __syncthreads();

    float v[15];
    #pragma unroll
    for (int q = 0; q < 15; ++q) v[q] = 0.0f;
    if (tid < BJ) {
        const float p0 = predL[0][tid], p1 = predL[1][tid], p2 = predL[2][tid];
        const float* sp = source + ((size_t)b * NPT + j0 + tid) * 3;
        const float s0 = sp[0], s1 = sp[1], s2 = sp[2];
        v[0] = s0; v[1] = s1; v[2] = s2;
        v[3] = p0; v[4] = p1; v[5] = p2;
        v[6]  = s0 * p0; v[7]  = s0 * p1; v[8]  = s0 * p2;
        v[9]  = s1 * p0; v[10] = s1 * p1; v[11] = s1 * p2;
        v[12] = s2 * p0; v[13] = s2 * p1; v[14] = s2 * p2;
    }
    #pragma unroll
    for (int q = 0; q < 15; ++q)
        #pragma unroll
        for (int off = 32; off > 0; off >>= 1)
            v[q] += __shfl_down(v[q], off);
    if (lane == 0) {
        #pragma unroll
        for (int q = 0; q < 15; ++q) fin[wave][q] = v[q];
    }
    __syncthreads();
    if (tid == 0) {
        float* o = partials + (((size_t)b << 4) + jt) * 16;
        #pragma unroll
        for (int q = 0; q < 15; ++q) {
            float s = 0.0f;
            #pragma unroll
            for (int w = 0; w < 8; ++w) s += fin[w][q];
            o[q] = s;
        }
    }
}

// ---------------------------------------------------------------------------
// Kernel B: per-batch 3x3 covariance -> SVD (Jacobi on S^T S) -> R, t
// ---------------------------------------------------------------------------
__device__ inline void jrot(float A[3][3], float V[3][3], int p, int q)
{
    const float apq = A[p][q];
    if (fabsf(apq) < 1e-28f) return;
    const float tau = (A[q][q] - A[p][p]) / (2.0f * apq);
    const float t   = (tau >= 0.0f ? 1.0f : -1.0f) / (fabsf(tau) + sqrtf(1.0f + tau * tau));
    const float c   = rsqrtf(1.0f + t * t);
    const float s   = t * c;
    const float app = A[p][p], aqq = A[q][q];
    A[p][p] = app - t * apq;
    A[q][q] = aqq + t * apq;
    A[p][q] = 0.0f; A[q][p] = 0.0f;
    const int r = 3 - p - q;
    const float arp = A[r][p], arq = A[r][q];
    A[r][p] = c * arp - s * arq; A[p][r] = A[r][p];
    A[r][q] = s * arp + c * arq; A[q][r] = A[r][q];
    #pragma unroll
    for (int rr = 0; rr < 3; ++rr) {
        const float vrp = V[rr][p], vrq = V[rr][q];
        V[rr][p] = c * vrp - s * vrq;
        V[rr][q] = s * vrp + c * vrq;
    }
}

__global__ void svd_finalize_kernel(const float* __restrict__ partials,
                                    float* __restrict__ out)
{
    const int b = threadIdx.x;
    if (b >= NB) return;

    float srcS[3] = {0, 0, 0}, predS[3] = {0, 0, 0}, SP[9] = {0, 0, 0, 0, 0, 0, 0, 0, 0};
    for (int p = 0; p < NJT; ++p) {
        const float* vv = partials + (((size_t)b << 4) + p) * 16;
        srcS[0] += vv[0]; srcS[1] += vv[1]; srcS[2] += vv[2];
        predS[0] += vv[3]; predS[1] += vv[4]; predS[2] += vv[5];
        #pragma unroll
        for (int q = 0; q < 9; ++q) SP[q] += vv[6 + q];
    }

    const float invN = 1.0f / (float)NPT;
    float ms[3], mt[3];
    #pragma unroll
    for (int c = 0; c < 3; ++c) { ms[c] = srcS[c] * invN; mt[c] = predS[c] * invN; }

    float S[3][3];
    #pragma unroll
    for (int c = 0; c < 3; ++c)
        #pragma unroll
        for (int d = 0; d < 3; ++d)
            S[c][d] = SP[c * 3 + d] - srcS[c] * predS[d] * invN;

    float A[3][3];
    #pragma unroll
    for (int i = 0; i < 3; ++i)
        #pragma unroll
        for (int j = 0; j < 3; ++j)
            A[i][j] = S[0][i] * S[0][j] + S[1][i] * S[1][j] + S[2][i] * S[2][j];

    float V[3][3] = {{1, 0, 0}, {0, 1, 0}, {0, 0, 1}};
    for (int sweep = 0; sweep < 12; ++sweep) {
        jrot(A, V, 0, 1);
        jrot(A, V, 0, 2);
        jrot(A, V, 1, 2);
    }

    float lam[3] = {A[0][0], A[1][1], A[2][2]};
    for (int i = 0; i < 2; ++i) {
        int mx = i;
        for (int j = i + 1; j < 3; ++j) if (lam[j] > lam[mx]) mx = j;
        if (mx != i) {
            const float tl = lam[i]; lam[i] = lam[mx]; lam[mx] = tl;
            #pragma unroll
            for (int r = 0; r < 3; ++r) {
                const float tv = V[r][i]; V[r][i] = V[r][mx]; V[r][mx] = tv;
            }
        }
    }

    float w0[3], w1[3], u1[3], u2[3], u3[3];
    #pragma unroll
    for (int r = 0; r < 3; ++r) {
        w0[r] = S[r][0] * V[0][0] + S[r][1] * V[1][0] + S[r][2] * V[2][0];
        w1[r] = S[r][0] * V[0][1] + S[r][1] * V[1][1] + S[r][2] * V[2][1];
    }
    const float n1 = sqrtf(w0[0] * w0[0] + w0[1] * w0[1] + w0[2] * w0[2]) + 1e-30f;
    #pragma unroll
    for (int r = 0; r < 3; ++r) u1[r] = w0[r] / n1;
    const float d01 = u1[0] * w1[0] + u1[1] * w1[1] + u1[2] * w1[2];
    #pragma unroll
    for (int r = 0; r < 3; ++r) u2[r] = w1[r] - d01 * u1[r];
    const float n2 = sqrtf(u2[0] * u2[0] + u2[1] * u2[1] + u2[2] * u2[2]) + 1e-30f;
    #pragma unroll
    for (int r = 0; r < 3; ++r) u2[r] /= n2;
    u3[0] = u1[1] * u2[2] - u1[2] * u2[1];
    u3[1] = u1[2] * u2[0] - u1[0] * u2[2];
    u3[2] = u1[0] * u2[1] - u1[1] * u2[0];

    const float detV =
        V[0][0] * (V[1][1] * V[2][2] - V[1][2] * V[2][1]) -
        V[0][1] * (V[1][0] * V[2][2] - V[1][2] * V[2][0]) +
        V[0][2] * (V[1][0] * V[2][1] - V[1][1] * V[2][0]);

    float R[3][3];
    #pragma unroll
    for (int r = 0; r < 3; ++r)
        #pragma unroll
        for (int c = 0; c < 3; ++c)
            R[r][c] = V[r][0] * u1[c] + V[r][1] * u2[c] + detV * V[r][2] * u3[c];

    #pragma unroll
    for (int r = 0; r < 3; ++r)
        #pragma unroll
        for (int c = 0; c < 3; ++c)
            out[b * 9 + r * 3 + c] = R[r][c];

    #pragma unroll
    for (int r = 0; r < 3; ++r) {
        const float tr = mt[r] - (R[r][0] * ms[0] + R[r][1] * ms[1] + R[r][2] * ms[2]);
        out[NB * 9 + b * 3 + r] = tr;
    }
}

extern "C" void kernel_launch(void* const* d_in, const int* in_sizes, int n_in,
                              void* d_out, int out_size, void* d_ws, size_t ws_size,
                              hipStream_t stream)
{
    const float* source  = (const float*)d_in[0];
    const float* target  = (const float*)d_in[1];
    const float* fsource = (const float*)d_in[2];
    const float* ftarget = (const float*)d_in[3];
    float* partials = (float*)d_ws;   // 256 blocks x 16 floats
    float* out = (float*)d_out;

    dim3 grid(NB, NJT);
    attn_partials_kernel<<<grid, NTHR, 0, stream>>>(source, target, fsource, ftarget, partials);
    svd_finalize_kernel<<<1, 64, 0, stream>>>(partials, out);
}

// Round 4
// 237.812 us; speedup vs baseline: 15.1771x; 1.3263x over previous
//
#include <hip/hip_runtime.h>
#include <math.h>
#include <stdint.h>

#define NB   16
#define NPT  2048
#define NF   512
#define BI   128
#define BJ   128
#define KB   32
#define NTHR 512
#define NJT  (NPT / BJ)   // 16
#define NIT  (NPT / BI)   // 16
#define NKC  (NF / KB)    // 16

// LDS geometry (bytes), shared by both kernels. Col-group = 16 cols x 32 k
// fp16, internally [k-half][k-group 4][row 4][col 16], padded stride 1056
// (=32B mod 128) -> staging writes 2-way-clean, tr-reads measured 0-conflict.
#define CGS    1056
#define PLANE  8448           // 8 col-groups (128 cols)
#define PLANE_H 4224
#define BUFB   33792          // fallback kernel: 4 planes of 8 cg
// new 128x256 kernel: A planes 8 cg, B planes 16 cg
#define BPLANE 16896
#define BUF2   50688          // Ahi(8448) Alo(8448) Bhi(16896) Blo(16896)

typedef _Float16 h4 __attribute__((ext_vector_type(4)));
typedef _Float16 h8 __attribute__((ext_vector_type(8)));
typedef float    f32x4 __attribute__((ext_vector_type(4)));

// ds_read_b64_tr_b16, NATURAL addressing (base + lane*8): 64 lanes cover a
// 512B [16k][16col] subtile; HW delivers lane l = col (l&15). [m156/m162]
#define TRR(dst, a) asm volatile("ds_read_b64_tr_b16 %0, %1" : "=v"(dst) : "v"(a))

__device__ __forceinline__ h8 cat(h4 a, h4 b) {
    return __builtin_shufflevector(a, b, 0, 1, 2, 3, 4, 5, 6, 7);
}

__device__ __forceinline__ void cvt4(const float4 v, h4& hi, h4& lo) {
    hi[0] = (_Float16)v.x; hi[1] = (_Float16)v.y;
    hi[2] = (_Float16)v.z; hi[3] = (_Float16)v.w;
    lo[0] = (_Float16)(v.x - (float)hi[0]);
    lo[1] = (_Float16)(v.y - (float)hi[1]);
    lo[2] = (_Float16)(v.z - (float)hi[2]);
    lo[3] = (_Float16)(v.w - (float)hi[3]);
}

__device__ __forceinline__ void cvt8(const float4 a, const float4 b, h8& hi, h8& lo) {
    hi[0] = (_Float16)a.x; hi[1] = (_Float16)a.y;
    hi[2] = (_Float16)a.z; hi[3] = (_Float16)a.w;
    hi[4] = (_Float16)b.x; hi[5] = (_Float16)b.y;
    hi[6] = (_Float16)b.z; hi[7] = (_Float16)b.w;
    lo[0] = (_Float16)(a.x - (float)hi[0]);
    lo[1] = (_Float16)(a.y - (float)hi[1]);
    lo[2] = (_Float16)(a.z - (float)hi[2]);
    lo[3] = (_Float16)(a.w - (float)hi[3]);
    lo[4] = (_Float16)(b.x - (float)hi[4]);
    lo[5] = (_Float16)(b.y - (float)hi[5]);
    lo[6] = (_Float16)(b.z - (float)hi[6]);
    lo[7] = (_Float16)(b.w - (float)hi[7]);
}

__device__ __forceinline__ int hoffB(int f, int n8) {
    // byte offset within a plane for an 8-col chunk (f row, cols n8*8..+7)
    return (n8 >> 1) * CGS + (f >> 4) * 512 + ((f >> 2) & 3) * 128
         + (f & 3) * 32 + (n8 & 1) * 16;
}

// ---------------------------------------------------------------------------
// Kernel A (main path): 128i x 256j logits tile per block, fp16 hi/lo split
// MFMA (3 terms), m4 x n4 register blocking, counted-lgkmcnt pipeline,
// i-split online softmax -> per-(b, ihalf, j) state written to ws.
// Grid (16 b, 8 jt, 2 ihalf) = 256 blocks, 512 thr, 1 block/CU.
// ---------------------------------------------------------------------------
__global__ __launch_bounds__(NTHR, 2)
void attn_state_kernel(const float* __restrict__ target,
                       const float* __restrict__ fsource,
                       const float* __restrict__ ftarget,
                       float* __restrict__ stw)   // [5][16*2*2048]
{
    const int b    = blockIdx.x;
    const int jt   = blockIdx.y;          // 0..7  (256-wide j tiles)
    const int ih   = blockIdx.z;          // 0..1  (i halves of 1024)
    const int j0   = jt * 256;
    const int tid  = threadIdx.x;
    const int lane = tid & 63;
    const int wave = tid >> 6;
    const int wi   = wave >> 2;           // 0..1: rows [wi*64, wi*64+64)
    const int wj   = wave & 3;            // 0..3: cols [wj*64, wj*64+64)
    const int lg   = lane >> 4;
    const int lr   = lane & 15;

    __shared__ __align__(16) unsigned char TIL[2][BUF2];
    __shared__ float  tgts[3][BI];
    __shared__ float  redM[2][256];
    __shared__ float4 redS[2][256];

    const uint32_t tilesBase = (uint32_t)(uintptr_t)&TIL[0][0];
    const uint32_t trLane    = (uint32_t)(lane * 8);
    const size_t   fbase     = (size_t)b * NF * NPT;

    // staging assignment: A chunk = tid (32f x 16 chunks); B chunks tid, tid+512
    const int fA  = tid >> 4,  n8A  = tid & 15;
    const int fB0 = tid >> 5,  n8B  = tid & 31;
    const int fB1 = (tid + 512) >> 5;
    const int offA  = hoffB(fA, n8A);
    const int offB0 = hoffB(fB0, n8B);
    const int offB1 = hoffB(fB1, n8B);

    float Mrun[4], Zrun[4], Yrun[4][3];
    #pragma unroll
    for (int n = 0; n < 4; ++n) {
        Mrun[n] = -3.0e38f; Zrun[n] = 0.0f;
        Yrun[n][0] = 0.0f; Yrun[n][1] = 0.0f; Yrun[n][2] = 0.0f;
    }

    for (int it = 0; it < 8; ++it) {
        const int i0 = ih * 1024 + it * BI;

        const float* pA  = ftarget + fbase + (size_t)fA  * NPT + i0 + n8A * 8;
        const float* pB0 = fsource + fbase + (size_t)fB0 * NPT + j0 + n8B * 8;
        const float* pB1 = fsource + fbase + (size_t)fB1 * NPT + j0 + n8B * 8;

        // ---- prologue: stage chunk 0 -> buf0, load target coords ----
        {
            float4 a0 = *(const float4*)(pA);
            float4 a1 = *(const float4*)(pA + 4);
            float4 b00 = *(const float4*)(pB0);
            float4 b01 = *(const float4*)(pB0 + 4);
            float4 b10 = *(const float4*)(pB1);
            float4 b11 = *(const float4*)(pB1 + 4);
            if (tid < BI) {
                const float* tp = target + ((size_t)b * NPT + i0 + tid) * 3;
                tgts[0][tid] = tp[0]; tgts[1][tid] = tp[1]; tgts[2][tid] = tp[2];
            }
            unsigned char* bp = (unsigned char*)&TIL[0][0];
            h8 hi, lo;
            cvt8(a0, a1, hi, lo);
            *(h8*)(bp + offA) = hi;  *(h8*)(bp + PLANE + offA) = lo;
            cvt8(b00, b01, hi, lo);
            *(h8*)(bp + 2 * PLANE + offB0) = hi;  *(h8*)(bp + 2 * PLANE + BPLANE + offB0) = lo;
            cvt8(b10, b11, hi, lo);
            *(h8*)(bp + 2 * PLANE + offB1) = hi;  *(h8*)(bp + 2 * PLANE + BPLANE + offB1) = lo;
        }
        __syncthreads();

        f32x4 acc[4][4];
        #pragma unroll
        for (int m = 0; m < 4; ++m)
            #pragma unroll
            for (int n = 0; n < 4; ++n)
                acc[m][n] = (f32x4){0.0f, 0.0f, 0.0f, 0.0f};

        for (int kc = 0; kc < NKC; ++kc) {
            const int buf = kc & 1;
            float4 ga0, ga1, gb00, gb01, gb10, gb11;
            if (kc + 1 < NKC) {
                const size_t ko = (size_t)(kc + 1) * KB * NPT;
                ga0  = *(const float4*)(pA + ko);
                ga1  = *(const float4*)(pA + ko + 4);
                gb00 = *(const float4*)(pB0 + ko);
                gb01 = *(const float4*)(pB0 + ko + 4);
                gb10 = *(const float4*)(pB1 + ko);
                gb11 = *(const float4*)(pB1 + ko + 4);
            }

            // ---- issue all 32 tr-reads: B(16) first, then A by m-frag ----
            const uint32_t bb  = tilesBase + (uint32_t)buf * BUF2;
            const uint32_t aHi = bb + (uint32_t)(wi * 4) * CGS + trLane;
            const uint32_t bHi = bb + 2u * PLANE + (uint32_t)(wj * 4) * CGS + trLane;
            h4 ta[4][2][2], tb[4][2][2];   // [frag][hi/lo][k-half]
            #pragma unroll
            for (int n = 0; n < 4; ++n) {
                TRR(tb[n][0][0], bHi + n * CGS);
                TRR(tb[n][0][1], bHi + n * CGS + 512);
                TRR(tb[n][1][0], bHi + n * CGS + BPLANE);
                TRR(tb[n][1][1], bHi + n * CGS + BPLANE + 512);
            }
            #pragma unroll
            for (int m = 0; m < 4; ++m) {
                TRR(ta[m][0][0], aHi + m * CGS);
                TRR(ta[m][0][1], aHi + m * CGS + 512);
                TRR(ta[m][1][0], aHi + m * CGS + PLANE);
                TRR(ta[m][1][1], aHi + m * CGS + PLANE + 512);
            }

            __builtin_amdgcn_s_setprio(1);
            h8 Bh[4], Bl[4];

#define MSTEP(M, WAITSTR) \
            asm volatile("s_waitcnt lgkmcnt(" WAITSTR ")" ::: "memory"); \
            __builtin_amdgcn_sched_barrier(0); \
            { const h8 Ah = cat(ta[M][0][0], ta[M][0][1]); \
              const h8 Al = cat(ta[M][1][0], ta[M][1][1]); \
              _Pragma("unroll") \
              for (int n = 0; n < 4; ++n) { \
                acc[M][n] = __builtin_amdgcn_mfma_f32_16x16x32_f16(Ah, Bh[n], acc[M][n], 0, 0, 0); \
                acc[M][n] = __builtin_amdgcn_mfma_f32_16x16x32_f16(Ah, Bl[n], acc[M][n], 0, 0, 0); \
                acc[M][n] = __builtin_amdgcn_mfma_f32_16x16x32_f16(Al, Bh[n], acc[M][n], 0, 0, 0); \
              } }

            // B(16)+A-m0(4) done when outstanding <= 12
            asm volatile("s_waitcnt lgkmcnt(12)" ::: "memory");
            __builtin_amdgcn_sched_barrier(0);
            #pragma unroll
            for (int n = 0; n < 4; ++n) {
                Bh[n] = cat(tb[n][0][0], tb[n][0][1]);
                Bl[n] = cat(tb[n][1][0], tb[n][1][1]);
            }
            {
                const h8 Ah = cat(ta[0][0][0], ta[0][0][1]);
                const h8 Al = cat(ta[0][1][0], ta[0][1][1]);
                #pragma unroll
                for (int n = 0; n < 4; ++n) {
                    acc[0][n] = __builtin_amdgcn_mfma_f32_16x16x32_f16(Ah, Bh[n], acc[0][n], 0, 0, 0);
                    acc[0][n] = __builtin_amdgcn_mfma_f32_16x16x32_f16(Ah, Bl[n], acc[0][n], 0, 0, 0);
                    acc[0][n] = __builtin_amdgcn_mfma_f32_16x16x32_f16(Al, Bh[n], acc[0][n], 0, 0, 0);
                }
            }
            MSTEP(1, "8")
            MSTEP(2, "4")
            MSTEP(3, "0")
#undef MSTEP
            __builtin_amdgcn_s_setprio(0);

            if (kc + 1 < NKC) {
                unsigned char* bp = (unsigned char*)&TIL[0][0] + (buf ^ 1) * BUF2;
                h8 hi, lo;
                cvt8(ga0, ga1, hi, lo);
                *(h8*)(bp + offA) = hi;  *(h8*)(bp + PLANE + offA) = lo;
                cvt8(gb00, gb01, hi, lo);
                *(h8*)(bp + 2 * PLANE + offB0) = hi;  *(h8*)(bp + 2 * PLANE + BPLANE + offB0) = lo;
                cvt8(gb10, gb11, hi, lo);
                *(h8*)(bp + 2 * PLANE + offB1) = hi;  *(h8*)(bp + 2 * PLANE + BPLANE + offB1) = lo;
                __syncthreads();
            }
        }

        // ---- online softmax update for this i-tile ----
        // D layout: col j = wj*64 + n*16 + lr, row i = wi*64 + m*16 + lg*4 + r
        #pragma unroll
        for (int n = 0; n < 4; ++n) {
            float m = acc[0][n][0];
            #pragma unroll
            for (int mm = 0; mm < 4; ++mm)
                #pragma unroll
                for (int r = 0; r < 4; ++r)
                    m = fmaxf(m, acc[mm][n][r]);
            m = fmaxf(m, __shfl_xor(m, 16));
            m = fmaxf(m, __shfl_xor(m, 32));
            if (lane < 16) redM[wi][wj * 64 + n * 16 + lr] = m;
        }
        __syncthreads();
        float mnew[4];
        #pragma unroll
        for (int n = 0; n < 4; ++n) {
            const int col = wj * 64 + n * 16 + lr;
            mnew[n] = fmaxf(Mrun[n], fmaxf(redM[0][col], redM[1][col]));
        }

        float z[4] = {0, 0, 0, 0}, y[4][3] = {{0,0,0},{0,0,0},{0,0,0},{0,0,0}};
        #pragma unroll
        for (int mm = 0; mm < 4; ++mm)
            #pragma unroll
            for (int r = 0; r < 4; ++r) {
                const int iL = wi * 64 + mm * 16 + lg * 4 + r;
                const float t0 = tgts[0][iL], t1 = tgts[1][iL], t2 = tgts[2][iL];
                #pragma unroll
                for (int n = 0; n < 4; ++n) {
                    const float e = __expf(acc[mm][n][r] - mnew[n]);
                    z[n] += e;
                    y[n][0] = fmaf(e, t0, y[n][0]);
                    y[n][1] = fmaf(e, t1, y[n][1]);
                    y[n][2] = fmaf(e, t2, y[n][2]);
                }
            }
        #pragma unroll
        for (int n = 0; n < 4; ++n) {
            #pragma unroll
            for (int off = 16; off <= 32; off <<= 1) {
                z[n]    += __shfl_xor(z[n], off);
                y[n][0] += __shfl_xor(y[n][0], off);
                y[n][1] += __shfl_xor(y[n][1], off);
                y[n][2] += __shfl_xor(y[n][2], off);
            }
            if (lane < 16)
                redS[wi][wj * 64 + n * 16 + lr] = make_float4(z[n], y[n][0], y[n][1], y[n][2]);
        }
        __syncthreads();
        #pragma unroll
        for (int n = 0; n < 4; ++n) {
            const int col = wj * 64 + n * 16 + lr;
            const float4 s0 = redS[0][col], s1 = redS[1][col];
            const float sc = __expf(Mrun[n] - mnew[n]);
            Zrun[n]    = Zrun[n]    * sc + s0.x + s1.x;
            Yrun[n][0] = Yrun[n][0] * sc + s0.y + s1.y;
            Yrun[n][1] = Yrun[n][1] * sc + s0.z + s1.z;
            Yrun[n][2] = Yrun[n][2] * sc + s0.w + s1.w;
            Mrun[n] = mnew[n];
        }
        __syncthreads();   // protect redM/redS & tiles before next it's staging
    }

    // ---- write per-column state (wi==0 waves hold the folded state too) ----
    if (wi == 0 && lane < 16) {
        #pragma unroll
        for (int n = 0; n < 4; ++n) {
            const int j   = j0 + wj * 64 + n * 16 + lr;
            const int idx = (b * 2 + ih) * NPT + j;
            stw[0 * (NB * 2 * NPT) + idx] = Mrun[n];
            stw[1 * (NB * 2 * NPT) + idx] = Zrun[n];
            stw[2 * (NB * 2 * NPT) + idx] = Yrun[n][0];
            stw[3 * (NB * 2 * NPT) + idx] = Yrun[n][1];
            stw[4 * (NB * 2 * NPT) + idx] = Yrun[n][2];
        }
    }
}

// ---------------------------------------------------------------------------
// Combine kernel: merge the two i-half softmax states per column, compute
// pred, then per-(b, 128-j-chunk) partial sums (15 values) for the SVD stage.
// ---------------------------------------------------------------------------
__global__ void combine_kernel(const float* __restrict__ source,
                               const float* __restrict__ stw,
                               float* __restrict__ partials)
{
    const int b   = blockIdx.x;
    const int jc  = blockIdx.y;     // 0..15
    const int tid = threadIdx.x;    // 128
    const int lane = tid & 63, wv = tid >> 6;
    const int j = jc * BJ + tid;
    const int SP = NB * 2 * NPT;
    const int i0 = (b * 2 + 0) * NPT + j;
    const int i1 = (b * 2 + 1) * NPT + j;

    __shared__ float fin2[2][15];

    const float ma = stw[i0],            mb = stw[i1];
    const float za = stw[SP + i0],       zb = stw[SP + i1];
    const float ms = fmaxf(ma, mb);
    const float sa = __expf(ma - ms), sb = __expf(mb - ms);
    const float z  = za * sa + zb * sb;
    const float iz = 1.0f / z;
    const float p0 = (stw[2 * SP + i0] * sa + stw[2 * SP + i1] * sb) * iz;
    const float p1 = (stw[3 * SP + i0] * sa + stw[3 * SP + i1] * sb) * iz;
    const float p2 = (stw[4 * SP + i0] * sa + stw[4 * SP + i1] * sb) * iz;

    const float* sp = source + ((size_t)b * NPT + j) * 3;
    const float s0 = sp[0], s1 = sp[1], s2 = sp[2];

    float v[15];
    v[0] = s0; v[1] = s1; v[2] = s2;
    v[3] = p0; v[4] = p1; v[5] = p2;
    v[6]  = s0 * p0; v[7]  = s0 * p1; v[8]  = s0 * p2;
    v[9]  = s1 * p0; v[10] = s1 * p1; v[11] = s1 * p2;
    v[12] = s2 * p0; v[13] = s2 * p1; v[14] = s2 * p2;

    #pragma unroll
    for (int q = 0; q < 15; ++q)
        #pragma unroll
        for (int off = 32; off > 0; off >>= 1)
            v[q] += __shfl_down(v[q], off);
    if (lane == 0) {
        #pragma unroll
        for (int q = 0; q < 15; ++q) fin2[wv][q] = v[q];
    }
    __syncthreads();
    if (tid == 0) {
        float* o = partials + (((size_t)b << 4) + jc) * 16;
        #pragma unroll
        for (int q = 0; q < 15; ++q) o[q] = fin2[0][q] + fin2[1][q];
    }
}

// ---------------------------------------------------------------------------
// Fallback kernel (round-3, proven): used only if ws_size is too small for
// the state buffer. 128x128 tile, full-i loop, writes partials directly.
// ---------------------------------------------------------------------------
__global__ __launch_bounds__(NTHR, 2)
void attn_partials_kernel(const float* __restrict__ source,
                          const float* __restrict__ target,
                          const float* __restrict__ fsource,
                          const float* __restrict__ ftarget,
                          float* __restrict__ partials)
{
    const int b    = blockIdx.x;
    const int jt   = blockIdx.y;
    const int j0   = jt * BJ;
    const int tid  = threadIdx.x;
    const int lane = tid & 63;
    const int wave = tid >> 6;
    const int wi   = wave >> 2;
    const int wj   = wave & 3;
    const int lg   = lane >> 4;
    const int lr   = lane & 15;

    __shared__ __align__(16) _Float16 TILES[2][4][PLANE_H];
    __shared__ float  tgts[3][BI];
    __shared__ float  redM[2][BJ];
    __shared__ float4 redS[2][BJ];
    __shared__ float  predL[3][BJ];
    __shared__ float  fin[8][15];

    const uint32_t tilesBase = (uint32_t)(uintptr_t)&TILES[0][0][0];
    const uint32_t trLane    = (uint32_t)(lane * 8);
    const size_t fbase = (size_t)b * NF * NPT;

    float Mrun[2], Zrun[2], Yrun[2][3];
    #pragma unroll
    for (int n = 0; n < 2; ++n) {
        Mrun[n] = -3.0e38f; Zrun[n] = 0.0f;
        Yrun[n][0] = 0.0f; Yrun[n][1] = 0.0f; Yrun[n][2] = 0.0f;
    }

    float4 gA[2], gB[2];

    for (int it = 0; it < NIT; ++it) {
        const int i0 = it * BI;
        #pragma unroll
        for (int p = 0; p < 2; ++p) {
            const int q = tid + p * NTHR;
            const int f = q >> 5, i4 = q & 31;
            gA[p] = *(const float4*)(ftarget + fbase + (size_t)f * NPT + i0 + i4 * 4);
            gB[p] = *(const float4*)(fsource + fbase + (size_t)f * NPT + j0 + i4 * 4);
        }
        if (tid < BI) {
            const float* tp = target + ((size_t)b * NPT + i0 + tid) * 3;
            tgts[0][tid] = tp[0]; tgts[1][tid] = tp[1]; tgts[2][tid] = tp[2];
        }
        #pragma unroll
        for (int p = 0; p < 2; ++p) {
            const int q = tid + p * NTHR;
            const int f = q >> 5, i4 = q & 31;
            const int hoff = (i4 >> 2) * 528 + (f >> 4) * 256 + ((f >> 2) & 3) * 64
                           + (f & 3) * 16 + (i4 & 3) * 4;
            _Float16* bp = &TILES[0][0][0];
            h4 hi, lo;
            cvt4(gA[p], hi, lo);
            *(h4*)(bp + hoff)               = hi;
            *(h4*)(bp + PLANE_H + hoff)     = lo;
            cvt4(gB[p], hi, lo);
            *(h4*)(bp + 2 * PLANE_H + hoff) = hi;
            *(h4*)(bp + 3 * PLANE_H + hoff) = lo;
        }
        __syncthreads();

        f32x4 acc[4][2];
        #pragma unroll
        for (int m = 0; m < 4; ++m)
            #pragma unroll
            for (int n = 0; n < 2; ++n)
                acc[m][n] = (f32x4){0.0f, 0.0f, 0.0f, 0.0f};

        for (int kc = 0; kc < NKC; ++kc) {
            const int buf = kc & 1;
            if (kc + 1 < NKC) {
                #pragma unroll
                for (int p = 0; p < 2; ++p) {
                    const int q = tid + p * NTHR;
                    const int f = q >> 5, i4 = q & 31;
                    const size_t row = (size_t)((kc + 1) * KB + f) * NPT;
                    gA[p] = *(const float4*)(ftarget + fbase + row + i0 + i4 * 4);
                    gB[p] = *(const float4*)(fsource + fbase + row + j0 + i4 * 4);
                }
            }
            const uint32_t bufB = tilesBase + (uint32_t)buf * BUFB;
            const uint32_t aHi  = bufB + (uint32_t)(wi * 4) * CGS + trLane;
            const uint32_t bHi  = bufB + 2u * PLANE + (uint32_t)(wj * 2) * CGS + trLane;
            h4 ta[4][2][2], tb[2][2][2];
            #pragma unroll
            for (int n = 0; n < 2; ++n) {
                TRR(tb[n][0][0], bHi + n * CGS);
                TRR(tb[n][0][1], bHi + n * CGS + 512);
                TRR(tb[n][1][0], bHi + n * CGS + PLANE);
                TRR(tb[n][1][1], bHi + n * CGS + PLANE + 512);
            }
            #pragma unroll
            for (int m = 0; m < 4; ++m) {
                TRR(ta[m][0][0], aHi + m * CGS);
                TRR(ta[m][0][1], aHi + m * CGS + 512);
                TRR(ta[m][1][0], aHi + m * CGS + PLANE);
                TRR(ta[m][1][1], aHi + m * CGS + PLANE + 512);
            }
            asm volatile("s_waitcnt lgkmcnt(0)" ::: "memory");
            __builtin_amdgcn_sched_barrier(0);

            h8 Bh[2], Bl[2];
            #pragma unroll
            for (int n = 0; n < 2; ++n) {
                Bh[n] = cat(tb[n][0][0], tb[n][0][1]);
                Bl[n] = cat(tb[n][1][0], tb[n][1][1]);
            }
            #pragma unroll
            for (int m = 0; m < 4; ++m) {
                const h8 Ah = cat(ta[m][0][0], ta[m][0][1]);
                const h8 Al = cat(ta[m][1][0], ta[m][1][1]);
                #pragma unroll
                for (int n = 0; n < 2; ++n) {
                    acc[m][n] = __builtin_amdgcn_mfma_f32_16x16x32_f16(Ah, Bh[n], acc[m][n], 0, 0, 0);
                    acc[m][n] = __builtin_amdgcn_mfma_f32_16x16x32_f16(Ah, Bl[n], acc[m][n], 0, 0, 0);
                    acc[m][n] = __builtin_amdgcn_mfma_f32_16x16x32_f16(Al, Bh[n], acc[m][n], 0, 0, 0);
                }
            }
            if (kc + 1 < NKC) {
                #pragma unroll
                for (int p = 0; p < 2; ++p) {
                    const int q = tid + p * NTHR;
                    const int f = q >> 5, i4 = q & 31;
                    const int hoff = (i4 >> 2) * 528 + (f >> 4) * 256 + ((f >> 2) & 3) * 64
                                   + (f & 3) * 16 + (i4 & 3) * 4;
                    _Float16* bp = &TILES[buf ^ 1][0][0];
                    h4 hi, lo;
                    cvt4(gA[p], hi, lo);
                    *(h4*)(bp + hoff)               = hi;
                    *(h4*)(bp + PLANE_H + hoff)     = lo;
                    cvt4(gB[p], hi, lo);
                    *(h4*)(bp + 2 * PLANE_H + hoff) = hi;
                    *(h4*)(bp + 3 * PLANE_H + hoff) = lo;
                }
                __syncthreads();
            }
        }

        #pragma unroll
        for (int n = 0; n < 2; ++n) {
            float m = acc[0][n][0];
            #pragma unroll
            for (int mm = 0; mm < 4; ++mm)
                #pragma unroll
                for (int r = 0; r < 4; ++r)
                    m = fmaxf(m, acc[mm][n][r]);
            m = fmaxf(m, __shfl_xor(m, 16));
            m = fmaxf(m, __shfl_xor(m, 32));
            if (lane < 16) redM[wi][wj * 32 + n * 16 + lr] = m;
        }
        __syncthreads();
        float mnew[2];
        #pragma unroll
        for (int n = 0; n < 2; ++n) {
            const int col = wj * 32 + n * 16 + lr;
            mnew[n] = fmaxf(Mrun[n], fmaxf(redM[0][col], redM[1][col]));
        }

        float z[2] = {0.0f, 0.0f}, y[2][3] = {{0, 0, 0}, {0, 0, 0}};
        #pragma unroll
        for (int mm = 0; mm < 4; ++mm)
            #pragma unroll
            for (int r = 0; r < 4; ++r) {
                const int iL = wi * 64 + mm * 16 + lg * 4 + r;
                const float t0 = tgts[0][iL], t1 = tgts[1][iL], t2 = tgts[2][iL];
                #pragma unroll
                for (int n = 0; n < 2; ++n) {
                    const float e = __expf(acc[mm][n][r] - mnew[n]);
                    z[n] += e;
                    y[n][0] = fmaf(e, t0, y[n][0]);
                    y[n][1] = fmaf(e, t1, y[n][1]);
                    y[n][2] = fmaf(e, t2, y[n][2]);
                }
            }
        #pragma unroll
        for (int n = 0; n < 2; ++n) {
            #pragma unroll
            for (int off = 16; off <= 32; off <<= 1) {
                z[n]    += __shfl_xor(z[n], off);
                y[n][0] += __shfl_xor(y[n][0], off);
                y[n][1] += __shfl_xor(y[n][1], off);
                y[n][2] += __shfl_xor(y[n][2], off);
            }
            if (lane < 16)
                redS[wi][wj * 32 + n * 16 + lr] = make_float4(z[n], y[n][0], y[n][1], y[n][2]);
        }
        __syncthreads();
        #pragma unroll
        for (int n = 0; n < 2; ++n) {
            const int col = wj * 32 + n * 16 + lr;
            const float4 s0 = redS[0][col], s1 = redS[1][col];
            const float sc = __expf(Mrun[n] - mnew[n]);
            Zrun[n]    = Zrun[n]    * sc + s0.x + s1.x;
            Yrun[n][0] = Yrun[n][0] * sc + s0.y + s1.y;
            Yrun[n][1] = Yrun[n][1] * sc + s0.z + s1.z;
            Yrun[n][2] = Yrun[n][2] * sc + s0.w + s1.w;
            Mrun[n] = mnew[n];
        }
    }

    if (lane < 16) {
        #pragma unroll
        for (int n = 0; n < 2; ++n) {
            const int col = wj * 32 + n * 16 + lr;
            const float iz = 1.0f / Zrun[n];
            predL[0][col] = Yrun[n][0] * iz;
            predL[1][col] = Yrun[n][1] * iz;
            predL[2][col] = Yrun[n][2] * iz;
        }
    }
    __syncthreads();

    float v[15];
    #pragma unroll
    for (int q = 0; q < 15; ++q) v[q] = 0.0f;
    if (tid < BJ) {
        const float p0 = predL[0][tid], p1 = predL[1][tid], p2 = predL[2][tid];
        const float* sp = source + ((size_t)b * NPT + j0 + tid) * 3;
        const float s0 = sp[0], s1 = sp[1], s2 = sp[2];
        v[0] = s0; v[1] = s1; v[2] = s2;
        v[3] = p0; v[4] = p1; v[5] = p2;
        v[6]  = s0 * p0; v[7]  = s0 * p1; v[8]  = s0 * p2;
        v[9]  = s1 * p0; v[10] = s1 * p1; v[11] = s1 * p2;
        v[12] = s2 * p0; v[13] = s2 * p1; v[14] = s2 * p2;
    }
    #pragma unroll
    for (int q = 0; q < 15; ++q)
        #pragma unroll
        for (int off = 32; off > 0; off >>= 1)
            v[q] += __shfl_down(v[q], off);
    if (lane == 0) {
        #pragma unroll
        for (int q = 0; q < 15; ++q) fin[wave][q] = v[q];
    }
    __syncthreads();
    if (tid == 0) {
        float* o = partials + (((size_t)b << 4) + jt) * 16;
        #pragma unroll
        for (int q = 0; q < 15; ++q) {
            float s = 0.0f;
            #pragma unroll
            for (int w = 0; w < 8; ++w) s += fin[w][q];
            o[q] = s;
        }
    }
}

// ---------------------------------------------------------------------------
// Kernel B: per-batch 3x3 covariance -> SVD (Jacobi on S^T S) -> R, t
// ---------------------------------------------------------------------------
__device__ inline void jrot(float A[3][3], float V[3][3], int p, int q)
{
    const float apq = A[p][q];
    if (fabsf(apq) < 1e-28f) return;
    const float tau = (A[q][q] - A[p][p]) / (2.0f * apq);
    const float t   = (tau >= 0.0f ? 1.0f : -1.0f) / (fabsf(tau) + sqrtf(1.0f + tau * tau));
    const float c   = rsqrtf(1.0f + t * t);
    const float s   = t * c;
    const float app = A[p][p], aqq = A[q][q];
    A[p][p] = app - t * apq;
    A[q][q] = aqq + t * apq;
    A[p][q] = 0.0f; A[q][p] = 0.0f;
    const int r = 3 - p - q;
    const float arp = A[r][p], arq = A[r][q];
    A[r][p] = c * arp - s * arq; A[p][r] = A[r][p];
    A[r][q] = s * arp + c * arq; A[q][r] = A[r][q];
    #pragma unroll
    for (int rr = 0; rr < 3; ++rr) {
        const float vrp = V[rr][p], vrq = V[rr][q];
        V[rr][p] = c * vrp - s * vrq;
        V[rr][q] = s * vrp + c * vrq;
    }
}

__global__ void svd_finalize_kernel(const float* __restrict__ partials,
                                    float* __restrict__ out)
{
    const int b = threadIdx.x;
    if (b >= NB) return;

    float srcS[3] = {0, 0, 0}, predS[3] = {0, 0, 0}, SP[9] = {0, 0, 0, 0, 0, 0, 0, 0, 0};
    for (int p = 0; p < NJT; ++p) {
        const float* vv = partials + (((size_t)b << 4) + p) * 16;
        srcS[0] += vv[0]; srcS[1] += vv[1]; srcS[2] += vv[2];
        predS[0] += vv[3]; predS[1] += vv[4]; predS[2] += vv[5];
        #pragma unroll
        for (int q = 0; q < 9; ++q) SP[q] += vv[6 + q];
    }

    const float invN = 1.0f / (float)NPT;
    float ms[3], mt[3];
    #pragma unroll
    for (int c = 0; c < 3; ++c) { ms[c] = srcS[c] * invN; mt[c] = predS[c] * invN; }

    float S[3][3];
    #pragma unroll
    for (int c = 0; c < 3; ++c)
        #pragma unroll
        for (int d = 0; d < 3; ++d)
            S[c][d] = SP[c * 3 + d] - srcS[c] * predS[d] * invN;

    float A[3][3];
    #pragma unroll
    for (int i = 0; i < 3; ++i)
        #pragma unroll
        for (int j = 0; j < 3; ++j)
            A[i][j] = S[0][i] * S[0][j] + S[1][i] * S[1][j] + S[2][i] * S[2][j];

    float V[3][3] = {{1, 0, 0}, {0, 1, 0}, {0, 0, 1}};
    for (int sweep = 0; sweep < 12; ++sweep) {
        jrot(A, V, 0, 1);
        jrot(A, V, 0, 2);
        jrot(A, V, 1, 2);
    }

    float lam[3] = {A[0][0], A[1][1], A[2][2]};
    for (int i = 0; i < 2; ++i) {
        int mx = i;
        for (int j = i + 1; j < 3; ++j) if (lam[j] > lam[mx]) mx = j;
        if (mx != i) {
            const float tl = lam[i]; lam[i] = lam[mx]; lam[mx] = tl;
            #pragma unroll
            for (int r = 0; r < 3; ++r) {
                const float tv = V[r][i]; V[r][i] = V[r][mx]; V[r][mx] = tv;
            }
        }
    }

    float w0[3], w1[3], u1[3], u2[3], u3[3];
    #pragma unroll
    for (int r = 0; r < 3; ++r) {
        w0[r] = S[r][0] * V[0][0] + S[r][1] * V[1][0] + S[r][2] * V[2][0];
        w1[r] = S[r][0] * V[0][1] + S[r][1] * V[1][1] + S[r][2] * V[2][1];
    }
    const float n1 = sqrtf(w0[0] * w0[0] + w0[1] * w0[1] + w0[2] * w0[2]) + 1e-30f;
    #pragma unroll
    for (int r = 0; r < 3; ++r) u1[r] = w0[r] / n1;
    const float d01 = u1[0] * w1[0] + u1[1] * w1[1] + u1[2] * w1[2];
    #pragma unroll
    for (int r = 0; r < 3; ++r) u2[r] = w1[r] - d01 * u1[r];
    const float n2 = sqrtf(u2[0] * u2[0] + u2[1] * u2[1] + u2[2] * u2[2]) + 1e-30f;
    #pragma unroll
    for (int r = 0; r < 3; ++r) u2[r] /= n2;
    u3[0] = u1[1] * u2[2] - u1[2] * u2[1];
    u3[1] = u1[2] * u2[0] - u1[0] * u2[2];
    u3[2] = u1[0] * u2[1] - u1[1] * u2[0];

    const float detV =
        V[0][0] * (V[1][1] * V[2][2] - V[1][2] * V[2][1]) -
        V[0][1] * (V[1][0] * V[2][2] - V[1][2] * V[2][0]) +
        V[0][2] * (V[1][0] * V[2][1] - V[1][1] * V[2][0]);

    float R[3][3];
    #pragma unroll
    for (int r = 0; r < 3; ++r)
        #pragma unroll
        for (int c = 0; c < 3; ++c)
            R[r][c] = V[r][0] * u1[c] + V[r][1] * u2[c] + detV * V[r][2] * u3[c];

    #pragma unroll
    for (int r = 0; r < 3; ++r)
        #pragma unroll
        for (int c = 0; c < 3; ++c)
            out[b * 9 + r * 3 + c] = R[r][c];

    #pragma unroll
    for (int r = 0; r < 3; ++r) {
        const float tr = mt[r] - (R[r][0] * ms[0] + R[r][1] * ms[1] + R[r][2] * ms[2]);
        out[NB * 9 + b * 3 + r] = tr;
    }
}

extern "C" void kernel_launch(void* const* d_in, const int* in_sizes, int n_in,
                              void* d_out, int out_size, void* d_ws, size_t ws_size,
                              hipStream_t stream)
{
    const float* source  = (const float*)d_in[0];
    const float* target  = (const float*)d_in[1];
    const float* fsource = (const float*)d_in[2];
    const float* ftarget = (const float*)d_in[3];
    float* out = (float*)d_out;

    const size_t ST_FLOATS = (size_t)5 * NB * 2 * NPT;              // state planes
    const size_t NEED = (ST_FLOATS + (size_t)NB * 16 * 16) * 4;     // + partials

    if (ws_size >= NEED) {
        float* stw      = (float*)d_ws;
        float* partials = (float*)d_ws + ST_FLOATS;
        attn_state_kernel<<<dim3(NB, 8, 2), NTHR, 0, stream>>>(target, fsource, ftarget, stw);
        combine_kernel<<<dim3(NB, 16), 128, 0, stream>>>(source, stw, partials);
        svd_finalize_kernel<<<1, 64, 0, stream>>>(partials, out);
    } else {
        float* partials = (float*)d_ws;
        attn_partials_kernel<<<dim3(NB, NJT), NTHR, 0, stream>>>(source, target, fsource, ftarget, partials);
        svd_finalize_kernel<<<1, 64, 0, stream>>>(partials, out);
    }
}